// Round 7
// baseline (225.541 us; speedup 1.0000x reference)
//
#include <hip/hip_runtime.h>
#include <hip/hip_bf16.h>

typedef float f32x4 __attribute__((ext_vector_type(4)));
typedef short bf16x8 __attribute__((ext_vector_type(8)));
typedef short s16x4 __attribute__((ext_vector_type(4)));

// Per-wave private LDS slice: a[16][136] shorts = 4352 B.
// Epilogue overlays the same region as o_f32[8][132] (4224 B).
#define WAVE_LDS_BYTES 4352

// Compiler-only memory fence (DS ops are in-order per wave; lanes lockstep).
#define LDS_FENCE() do { asm volatile("" ::: "memory"); \
                         __builtin_amdgcn_sched_barrier(0); } while (0)

__device__ __forceinline__ unsigned short f2bf(float f) {
    union { float f; unsigned int u; } v; v.f = f;
    unsigned int u = v.u;
    u += 0x7FFFu + ((u >> 16) & 1u);   // round-to-nearest-even
    return (unsigned short)(u >> 16);
}

__device__ __forceinline__ float bf2f(short b) {
    union { unsigned int u; float f; } v;
    v.u = ((unsigned int)(unsigned short)b) << 16;
    return v.f;
}

// w_eff[o][h] = (w1[o][h] + w2[o][h]) * weight[h], bf16, row-major [128][128]
__global__ void prep_weights_kernel(const float* __restrict__ w1,
                                    const float* __restrict__ w2,
                                    const float* __restrict__ weight,
                                    unsigned short* __restrict__ weff) {
    int idx = blockIdx.x * 256 + threadIdx.x;   // 64 blocks * 256 = 16384
    int h = idx & 127;
    weff[idx] = f2bf((w1[idx] + w2[idx]) * weight[h]);
}

#define TILES_TOTAL 4096      // 262144 rows / 64 rows-per-tile
#define GRID_BLOCKS 2048      // 8 blocks/CU * 256 CU; 2 tiles per block

// Zero-barrier, wave-private, persistent blocks; NT stores keep outputs out of L3.
__launch_bounds__(256, 8)
__global__ void fused_rms_gemm_kernel(const float* __restrict__ residual,
                                      const float* __restrict__ attn,
                                      const float* __restrict__ moe,
                                      const unsigned short* __restrict__ weff,
                                      float* __restrict__ combined,
                                      float* __restrict__ nres) {
    __shared__ __align__(16) unsigned char smem[4 * WAVE_LDS_BYTES];   // 17408 B

    const int t = threadIdx.x;
    const int w = t >> 6;
    const int l = t & 63;
    unsigned char* wbase = smem + w * WAVE_LDS_BYTES;
    short* a_s16 = (short*)wbase;                         // [16][136] bf16 add-tile
    float* o_f32 = (float*)wbase;                         // [8][132] epilogue overlay

    const int half = l >> 5;          // which of 2 rows per iteration
    const int c4 = l & 31;            // f32x4 slot within a row
    const int lq = l >> 4;            // k-slot group 0..3
    const int lr = l & 15;            // A-row / weff-row within 16

    for (int tile = blockIdx.x; tile < TILES_TOTAL; tile += GRID_BLOCKS) {
        const long grow0 = ((long)tile * 4 + w) * 16;     // first global row of wave

        // ---- Phase 1: streaming add/store + bf16 pack to LDS ----
        const long base0 = (grow0 + half) * 128 + c4 * 4; // iter stride = 256 floats
        f32x4 a0 = *(const f32x4*)(residual + base0);
        f32x4 b0 = *(const f32x4*)(attn + base0);
        f32x4 m0 = *(const f32x4*)(moe + base0);
        f32x4 a1 = *(const f32x4*)(residual + base0 + 256);
        f32x4 b1 = *(const f32x4*)(attn + base0 + 256);
        f32x4 m1 = *(const f32x4*)(moe + base0 + 256);
#pragma unroll
        for (int i = 0; i < 8; ++i) {
            f32x4 a = (i & 1) ? a1 : a0;
            f32x4 b = (i & 1) ? b1 : b0;
            f32x4 m = (i & 1) ? m1 : m0;
            if (i + 2 < 8) {                              // refill freed slot
                const long nb = base0 + (i + 2) * 256;
                if (i & 1) { a1 = *(const f32x4*)(residual + nb);
                             b1 = *(const f32x4*)(attn + nb);
                             m1 = *(const f32x4*)(moe + nb); }
                else       { a0 = *(const f32x4*)(residual + nb);
                             b0 = *(const f32x4*)(attn + nb);
                             m0 = *(const f32x4*)(moe + nb); }
            }
            f32x4 s = a + b;
            __builtin_nontemporal_store(s + m, (f32x4*)(nres + base0 + i * 256));
            s16x4 pk;
            pk.x = (short)f2bf(s.x);
            pk.y = (short)f2bf(s.y);
            pk.z = (short)f2bf(s.z);
            pk.w = (short)f2bf(s.w);
            *(s16x4*)(a_s16 + (i * 2 + half) * 136 + c4 * 4) = pk;
        }
        LDS_FENCE();   // all lanes' a_s16 writes precede phase-2 reads

        // ---- Phase 2: fragments, sumsq-from-fragments, MFMA ----
        bf16x8 afrag[4];
#pragma unroll
        for (int kk = 0; kk < 4; ++kk)
            afrag[kk] = *(const bf16x8*)(a_s16 + lr * 136 + kk * 32 + lq * 8);

        // sumsq of row lr: this lane's 32 elems, then combine the 4 lq-quarters.
        float p = 0.f;
#pragma unroll
        for (int kk = 0; kk < 4; ++kk)
#pragma unroll
            for (int e = 0; e < 8; ++e) {
                float f = bf2f(afrag[kk][e]);
                p += f * f;
            }
        p += __shfl_xor(p, 16);
        p += __shfl_xor(p, 32);
        const float scale = rsqrtf(p * (1.0f / 128.0f) + 1e-5f);  // row lr's scale

        f32x4 acc[8];
#pragma unroll
        for (int n = 0; n < 8; ++n) {
            acc[n] = (f32x4){0.f, 0.f, 0.f, 0.f};
            const unsigned short* wp = weff + (n * 16 + lr) * 128 + lq * 8;
#pragma unroll
            for (int kk = 0; kk < 4; ++kk) {
                bf16x8 bf = *(const bf16x8*)(wp + kk * 32);
                acc[n] = __builtin_amdgcn_mfma_f32_16x16x32_bf16(afrag[kk], bf, acc[n], 0, 0, 0);
            }
        }

        // per-lane scales for C rows lq*4+j: fetch from lane lq*4+j (lr == row)
        float sc[4];
#pragma unroll
        for (int j = 0; j < 4; ++j)
            sc[j] = __shfl(scale, lq * 4 + j);

        LDS_FENCE();   // afrag LDS reads complete before o_f32 overlay writes

        // ---- Phase 3: epilogue via wave-private LDS transpose, NT stores ----
        // C/D layout: col = lane&15 (weff row), row = lq*4 + j  [HW-verified]
#pragma unroll
        for (int r2 = 0; r2 < 2; ++r2) {
            if ((lq >> 1) == r2) {
                const int rbase = (lq & 1) * 4;  // row within this 8-row round
#pragma unroll
                for (int n = 0; n < 8; ++n)
#pragma unroll
                    for (int j = 0; j < 4; ++j)
                        o_f32[(rbase + j) * 132 + n * 16 + lr] = acc[n][j] * sc[j];
            }
            LDS_FENCE();   // o_f32 writes precede reads
#pragma unroll
            for (int k = 0; k < 4; ++k) {
                const int row = k * 2 + half;    // 2 rows per instruction (1KB)
                f32x4 v = *(const f32x4*)(o_f32 + row * 132 + c4 * 4);
                __builtin_nontemporal_store(
                    v, (f32x4*)(combined + (grow0 + r2 * 8 + row) * 128 + c4 * 4));
            }
            LDS_FENCE();   // round-r2 reads precede round-(r2+1) overwrites
        }
    }
}

extern "C" void kernel_launch(void* const* d_in, const int* in_sizes, int n_in,
                              void* d_out, int out_size, void* d_ws, size_t ws_size,
                              hipStream_t stream) {
    const float* residual = (const float*)d_in[0];
    const float* attn     = (const float*)d_in[1];
    const float* moe      = (const float*)d_in[2];
    const float* weight   = (const float*)d_in[3];
    const float* w1       = (const float*)d_in[4];
    const float* w2       = (const float*)d_in[5];

    unsigned short* weff = (unsigned short*)d_ws;  // 32 KB scratch

    const int total = in_sizes[0];                 // B*S*H = 33,554,432
    float* combined = (float*)d_out;
    float* nres = combined + (size_t)total;

    prep_weights_kernel<<<64, 256, 0, stream>>>(w1, w2, weight, weff);
    fused_rms_gemm_kernel<<<GRID_BLOCKS, 256, 0, stream>>>(
        residual, attn, moe, weff, combined, nres);
}

// Round 8
// 135.199 us; speedup vs baseline: 1.6682x; 1.6682x over previous
//
#include <hip/hip_runtime.h>
#include <hip/hip_bf16.h>

typedef float f32x4 __attribute__((ext_vector_type(4)));
typedef short bf16x8 __attribute__((ext_vector_type(8)));
typedef short s16x4 __attribute__((ext_vector_type(4)));

#define LDS_STRIDE 136      // shorts per A-row (272 B, 16B-aligned, non-pow2)
#define OUT_STRIDE 132      // floats per staged output row (528 B)

__device__ __forceinline__ unsigned short f2bf(float f) {
    union { float f; unsigned int u; } v; v.f = f;
    unsigned int u = v.u;
    u += 0x7FFFu + ((u >> 16) & 1u);   // round-to-nearest-even
    return (unsigned short)(u >> 16);
}

__device__ __forceinline__ float bf2f(short b) {
    union { unsigned int u; float f; } v;
    v.u = ((unsigned int)(unsigned short)b) << 16;
    return v.f;
}

// w_eff[o][h] = (w1[o][h] + w2[o][h]) * weight[h], bf16, row-major [128][128]
__global__ void prep_weights_kernel(const float* __restrict__ w1,
                                    const float* __restrict__ w2,
                                    const float* __restrict__ weight,
                                    unsigned short* __restrict__ weff) {
    int idx = blockIdx.x * 256 + threadIdx.x;   // 64 blocks * 256 = 16384
    int h = idx & 127;
    weff[idx] = f2bf((w1[idx] + w2[idx]) * weight[h]);
}

// R2 base (block-coop, barriers, B-in-regs) + phase-1 stream separation +
// frag-based sumsq (no per-iteration shfl chains, no scale_lds).
__launch_bounds__(256)
__global__ void fused_rms_gemm_kernel(const float* __restrict__ residual,
                                      const float* __restrict__ attn,
                                      const float* __restrict__ moe,
                                      const unsigned short* __restrict__ weff,
                                      float* __restrict__ combined,
                                      float* __restrict__ nres) {
    // Phase 1/2: bf16 A-tile [64][136] (17408 B). Epilogue overlays f32 [32][132] (16896 B).
    __shared__ __align__(16) unsigned char smem[64 * LDS_STRIDE * 2];
    short* a_lds = (short*)smem;
    float* o_f32 = (float*)smem;

    const int t = threadIdx.x;
    const int w = t >> 6;            // wave 0..3
    const int l = t & 63;
    const int half = l >> 5;         // which of 2 rows per iteration
    const int c4 = l & 31;           // f32x4 slot within a row
    const long row0 = (long)blockIdx.x * 64;

    // ---- Phase 1A: PURE READ burst (residual+attn only), s[] kept in regs ----
    // wave w owns rows [w*16, w*16+16); iter i covers rows w*16+i*2+{0,1}
    const long base0 = (row0 + w * 16 + half) * 128 + c4 * 4;  // iter stride 256
    f32x4 s[8];
    {
        f32x4 a0 = *(const f32x4*)(residual + base0);
        f32x4 b0 = *(const f32x4*)(attn + base0);
        f32x4 a1 = *(const f32x4*)(residual + base0 + 256);
        f32x4 b1 = *(const f32x4*)(attn + base0 + 256);
#pragma unroll
        for (int i = 0; i < 8; ++i) {
            f32x4 a = (i & 1) ? a1 : a0;
            f32x4 b = (i & 1) ? b1 : b0;
            if (i + 2 < 8) {                       // refill the slot just freed
                const long nb = base0 + (i + 2) * 256;
                if (i & 1) { a1 = *(const f32x4*)(residual + nb);
                             b1 = *(const f32x4*)(attn + nb); }
                else       { a0 = *(const f32x4*)(residual + nb);
                             b0 = *(const f32x4*)(attn + nb); }
            }
            s[i] = a + b;
            s16x4 pk;
            pk.x = (short)f2bf(s[i].x);
            pk.y = (short)f2bf(s[i].y);
            pk.z = (short)f2bf(s[i].z);
            pk.w = (short)f2bf(s[i].w);
            *(s16x4*)(a_lds + (w * 16 + i * 2 + half) * LDS_STRIDE + c4 * 4) = pk;
        }
    }

    // ---- Phase 1B: 1R+1W burst (moe read, nres write) ----
    {
        f32x4 m0 = *(const f32x4*)(moe + base0);
        f32x4 m1 = *(const f32x4*)(moe + base0 + 256);
#pragma unroll
        for (int i = 0; i < 8; ++i) {
            f32x4 m = (i & 1) ? m1 : m0;
            if (i + 2 < 8) {
                const long nb = base0 + (i + 2) * 256;
                if (i & 1) m1 = *(const f32x4*)(moe + nb);
                else       m0 = *(const f32x4*)(moe + nb);
            }
            *(f32x4*)(nres + base0 + i * 256) = s[i] + m;
        }
    }
    __syncthreads();

    // ---- Phase 2: frags, frag-based sumsq, MFMA, scale folded into acc ----
    const int lq = l >> 4;           // k-slot group 0..3
    const int lr = l & 15;           // A-row / weff-row within 16

    // B frags: lane holds w_eff[o = w*32 + n*16 + lr][kk*32 + lq*8 .. +7]
    bf16x8 bfrag[2][4];
#pragma unroll
    for (int n = 0; n < 2; ++n) {
        const unsigned short* wp = weff + (w * 32 + n * 16 + lr) * 128 + lq * 8;
#pragma unroll
        for (int kk = 0; kk < 4; ++kk)
            bfrag[n][kk] = *(const bf16x8*)(wp + kk * 32);
    }

    f32x4 acc[4][2] = {};
#pragma unroll
    for (int rt = 0; rt < 4; ++rt) {
        bf16x8 afrag[4];
        const short* ap = a_lds + (rt * 16 + lr) * LDS_STRIDE + lq * 8;
#pragma unroll
        for (int kk = 0; kk < 4; ++kk)
            afrag[kk] = *(const bf16x8*)(ap + kk * 32);

        // sumsq of row rt*16+lr: this lane's 32 elems + combine 4 lq-quarters
        float p = 0.f;
#pragma unroll
        for (int kk = 0; kk < 4; ++kk)
#pragma unroll
            for (int e = 0; e < 8; ++e) {
                float f = bf2f(afrag[kk][e]);
                p += f * f;
            }
        p += __shfl_xor(p, 16);
        p += __shfl_xor(p, 32);
        const float scl = rsqrtf(p * (1.0f / 128.0f) + 1e-5f);  // row rt*16+lr

#pragma unroll
        for (int kk = 0; kk < 4; ++kk) {
            acc[rt][0] = __builtin_amdgcn_mfma_f32_16x16x32_bf16(afrag[kk], bfrag[0][kk], acc[rt][0], 0, 0, 0);
            acc[rt][1] = __builtin_amdgcn_mfma_f32_16x16x32_bf16(afrag[kk], bfrag[1][kk], acc[rt][1], 0, 0, 0);
        }
        // C/D row of reg j is lq*4+j -> scale = scl of lane with lr == lq*4+j
#pragma unroll
        for (int j = 0; j < 4; ++j) {
            const float sj = __shfl(scl, lq * 4 + j);
            acc[rt][0][j] *= sj;
            acc[rt][1][j] *= sj;
        }
    }
    __syncthreads();   // all a_lds reads done; smem reused as o_f32

    // ---- Epilogue: stage via LDS, store combined as 1KB-contiguous f32x4 ----
    // C/D layout: col = lane&15, row = lq*4 + j  [HW-verified]
#pragma unroll
    for (int h = 0; h < 2; ++h) {
#pragma unroll
        for (int rt2 = 0; rt2 < 2; ++rt2) {
            const int rt = h * 2 + rt2;
#pragma unroll
            for (int j = 0; j < 4; ++j) {
                const int rloc = rt2 * 16 + lq * 4 + j;   // row within 32-row group
                o_f32[rloc * OUT_STRIDE + w * 32 + lr]      = acc[rt][0][j];
                o_f32[rloc * OUT_STRIDE + w * 32 + 16 + lr] = acc[rt][1][j];
            }
        }
        __syncthreads();
#pragma unroll
        for (int k = 0; k < 4; ++k) {
            const int c = k * 256 + t;                // 0..1023 f32x4 chunks
            const int row = c >> 5;
            const int col = (c & 31) * 4;
            f32x4 v = *(const f32x4*)(o_f32 + row * OUT_STRIDE + col);
            *(f32x4*)(combined + (row0 + h * 32 + row) * 128 + col) = v;
        }
        if (h == 0) __syncthreads();   // protect o_f32 before round-1 writes
    }
}

extern "C" void kernel_launch(void* const* d_in, const int* in_sizes, int n_in,
                              void* d_out, int out_size, void* d_ws, size_t ws_size,
                              hipStream_t stream) {
    const float* residual = (const float*)d_in[0];
    const float* attn     = (const float*)d_in[1];
    const float* moe      = (const float*)d_in[2];
    const float* weight   = (const float*)d_in[3];
    const float* w1       = (const float*)d_in[4];
    const float* w2       = (const float*)d_in[5];

    unsigned short* weff = (unsigned short*)d_ws;  // 32 KB scratch

    const int total = in_sizes[0];                 // B*S*H = 33,554,432
    const int rows = total / 128;                  // 262,144
    float* combined = (float*)d_out;
    float* nres = combined + (size_t)total;

    prep_weights_kernel<<<64, 256, 0, stream>>>(w1, w2, weight, weff);
    fused_rms_gemm_kernel<<<rows / 64, 256, 0, stream>>>(
        residual, attn, moe, weff, combined, nres);
}

// Round 9
// 134.116 us; speedup vs baseline: 1.6817x; 1.0081x over previous
//
#include <hip/hip_runtime.h>
#include <hip/hip_bf16.h>

typedef float f32x4 __attribute__((ext_vector_type(4)));
typedef short bf16x8 __attribute__((ext_vector_type(8)));
typedef short s16x4 __attribute__((ext_vector_type(4)));

#define LDS_STRIDE 136      // shorts per A-row (272 B, 16B-aligned, non-pow2)
#define OUT_STRIDE 132      // floats per staged output row (528 B)

__device__ __forceinline__ unsigned short f2bf(float f) {
    union { float f; unsigned int u; } v; v.f = f;
    unsigned int u = v.u;
    u += 0x7FFFu + ((u >> 16) & 1u);   // round-to-nearest-even
    return (unsigned short)(u >> 16);
}

__device__ __forceinline__ float bf2f(short b) {
    union { unsigned int u; float f; } v;
    v.u = ((unsigned int)(unsigned short)b) << 16;
    return v.f;
}

// w_eff[o][h] = (w1[o][h] + w2[o][h]) * weight[h], bf16, row-major [128][128]
__global__ void prep_weights_kernel(const float* __restrict__ w1,
                                    const float* __restrict__ w2,
                                    const float* __restrict__ weight,
                                    unsigned short* __restrict__ weff) {
    int idx = blockIdx.x * 256 + threadIdx.x;   // 64 blocks * 256 = 16384
    int h = idx & 127;
    weff[idx] = f2bf((w1[idx] + w2[idx]) * weight[h]);
}

// R8 base + FULL phase-1 stream separation: 2R burst / 1R burst / 1W burst.
// DRAM read<->write turnaround is the measured lever (R8: -15us from partial sep).
__launch_bounds__(256)
__global__ void fused_rms_gemm_kernel(const float* __restrict__ residual,
                                      const float* __restrict__ attn,
                                      const float* __restrict__ moe,
                                      const unsigned short* __restrict__ weff,
                                      float* __restrict__ combined,
                                      float* __restrict__ nres) {
    // Phase 1/2: bf16 A-tile [64][136] (17408 B). Epilogue overlays f32 [32][132] (16896 B).
    __shared__ __align__(16) unsigned char smem[64 * LDS_STRIDE * 2];
    short* a_lds = (short*)smem;
    float* o_f32 = (float*)smem;

    const int t = threadIdx.x;
    const int w = t >> 6;            // wave 0..3
    const int l = t & 63;
    const int half = l >> 5;         // which of 2 rows per iteration
    const int c4 = l & 31;           // f32x4 slot within a row
    const long row0 = (long)blockIdx.x * 64;

    // ---- Phase 1A: PURE 2R burst (residual+attn), s[] in regs, bf16 -> LDS ----
    // wave w owns rows [w*16, w*16+16); iter i covers rows w*16+i*2+{0,1}
    const long base0 = (row0 + w * 16 + half) * 128 + c4 * 4;  // iter stride 256
    f32x4 s[8];
    {
        f32x4 a0 = *(const f32x4*)(residual + base0);
        f32x4 b0 = *(const f32x4*)(attn + base0);
        f32x4 a1 = *(const f32x4*)(residual + base0 + 256);
        f32x4 b1 = *(const f32x4*)(attn + base0 + 256);
#pragma unroll
        for (int i = 0; i < 8; ++i) {
            f32x4 a = (i & 1) ? a1 : a0;
            f32x4 b = (i & 1) ? b1 : b0;
            if (i + 2 < 8) {                       // refill the slot just freed
                const long nb = base0 + (i + 2) * 256;
                if (i & 1) { a1 = *(const f32x4*)(residual + nb);
                             b1 = *(const f32x4*)(attn + nb); }
                else       { a0 = *(const f32x4*)(residual + nb);
                             b0 = *(const f32x4*)(attn + nb); }
            }
            s[i] = a + b;
            s16x4 pk;
            pk.x = (short)f2bf(s[i].x);
            pk.y = (short)f2bf(s[i].y);
            pk.z = (short)f2bf(s[i].z);
            pk.w = (short)f2bf(s[i].w);
            *(s16x4*)(a_lds + (w * 16 + i * 2 + half) * LDS_STRIDE + c4 * 4) = pk;
        }
    }

    // ---- Phase 1B: PURE 1R burst (all 8 moe loads in flight) ----
    f32x4 m[8];
#pragma unroll
    for (int i = 0; i < 8; ++i)
        m[i] = *(const f32x4*)(moe + base0 + i * 256);
#pragma unroll
    for (int i = 0; i < 8; ++i)
        m[i] = s[i] + m[i];

    // ---- Phase 1C: PURE 1W burst (8 nres stores) ----
#pragma unroll
    for (int i = 0; i < 8; ++i)
        *(f32x4*)(nres + base0 + i * 256) = m[i];

    __syncthreads();

    // ---- Phase 2: frags, frag-based sumsq, MFMA, scale folded into acc ----
    const int lq = l >> 4;           // k-slot group 0..3
    const int lr = l & 15;           // A-row / weff-row within 16

    // B frags: lane holds w_eff[o = w*32 + n*16 + lr][kk*32 + lq*8 .. +7]
    bf16x8 bfrag[2][4];
#pragma unroll
    for (int n = 0; n < 2; ++n) {
        const unsigned short* wp = weff + (w * 32 + n * 16 + lr) * 128 + lq * 8;
#pragma unroll
        for (int kk = 0; kk < 4; ++kk)
            bfrag[n][kk] = *(const bf16x8*)(wp + kk * 32);
    }

    f32x4 acc[4][2] = {};
#pragma unroll
    for (int rt = 0; rt < 4; ++rt) {
        bf16x8 afrag[4];
        const short* ap = a_lds + (rt * 16 + lr) * LDS_STRIDE + lq * 8;
#pragma unroll
        for (int kk = 0; kk < 4; ++kk)
            afrag[kk] = *(const bf16x8*)(ap + kk * 32);

        // sumsq of row rt*16+lr: this lane's 32 elems + combine 4 lq-quarters
        float p = 0.f;
#pragma unroll
        for (int kk = 0; kk < 4; ++kk)
#pragma unroll
            for (int e = 0; e < 8; ++e) {
                float f = bf2f(afrag[kk][e]);
                p += f * f;
            }
        p += __shfl_xor(p, 16);
        p += __shfl_xor(p, 32);
        const float scl = rsqrtf(p * (1.0f / 128.0f) + 1e-5f);  // row rt*16+lr

#pragma unroll
        for (int kk = 0; kk < 4; ++kk) {
            acc[rt][0] = __builtin_amdgcn_mfma_f32_16x16x32_bf16(afrag[kk], bfrag[0][kk], acc[rt][0], 0, 0, 0);
            acc[rt][1] = __builtin_amdgcn_mfma_f32_16x16x32_bf16(afrag[kk], bfrag[1][kk], acc[rt][1], 0, 0, 0);
        }
        // C/D row of reg j is lq*4+j -> scale = scl of lane with lr == lq*4+j
#pragma unroll
        for (int j = 0; j < 4; ++j) {
            const float sj = __shfl(scl, lq * 4 + j);
            acc[rt][0][j] *= sj;
            acc[rt][1][j] *= sj;
        }
    }
    __syncthreads();   // all a_lds reads done; smem reused as o_f32

    // ---- Epilogue: stage via LDS, store combined as 1KB-contiguous f32x4 ----
    // C/D layout: col = lane&15, row = lq*4 + j  [HW-verified]
#pragma unroll
    for (int h = 0; h < 2; ++h) {
#pragma unroll
        for (int rt2 = 0; rt2 < 2; ++rt2) {
            const int rt = h * 2 + rt2;
#pragma unroll
            for (int j = 0; j < 4; ++j) {
                const int rloc = rt2 * 16 + lq * 4 + j;   // row within 32-row group
                o_f32[rloc * OUT_STRIDE + w * 32 + lr]      = acc[rt][0][j];
                o_f32[rloc * OUT_STRIDE + w * 32 + 16 + lr] = acc[rt][1][j];
            }
        }
        __syncthreads();
#pragma unroll
        for (int k = 0; k < 4; ++k) {
            const int c = k * 256 + t;                // 0..1023 f32x4 chunks
            const int row = c >> 5;
            const int col = (c & 31) * 4;
            f32x4 v = *(const f32x4*)(o_f32 + row * OUT_STRIDE + col);
            *(f32x4*)(combined + (row0 + h * 32 + row) * 128 + col) = v;
        }
        if (h == 0) __syncthreads();   // protect o_f32 before round-1 writes
    }
}

extern "C" void kernel_launch(void* const* d_in, const int* in_sizes, int n_in,
                              void* d_out, int out_size, void* d_ws, size_t ws_size,
                              hipStream_t stream) {
    const float* residual = (const float*)d_in[0];
    const float* attn     = (const float*)d_in[1];
    const float* moe      = (const float*)d_in[2];
    const float* weight   = (const float*)d_in[3];
    const float* w1       = (const float*)d_in[4];
    const float* w2       = (const float*)d_in[5];

    unsigned short* weff = (unsigned short*)d_ws;  // 32 KB scratch

    const int total = in_sizes[0];                 // B*S*H = 33,554,432
    const int rows = total / 128;                  // 262,144
    float* combined = (float*)d_out;
    float* nres = combined + (size_t)total;

    prep_weights_kernel<<<64, 256, 0, stream>>>(w1, w2, weight, weff);
    fused_rms_gemm_kernel<<<rows / 64, 256, 0, stream>>>(
        residual, attn, moe, weff, combined, nres);
}